// Round 2
// baseline (575.714 us; speedup 1.0000x reference)
//
#include <hip/hip_runtime.h>

// TopKActivation: per row of [4096, 16384] fp32, keep top-k (k=128), zero rest.
// R5 theory: 164us kernel with HBM 30% / VALU 25% / 0 bank conflicts ==
// latency-bound. NT=1024 allowed only 2 blocks/CU (2 rows in flight); barrier +
// wave0-bisect phases left HBM idle. This version:
//   * NT=512, PER_T=32 (keys register-resident, __launch_bounds__(512,8) pins
//     <=64 VGPR -> 4 blocks/CU = 4 independent rows in flight).
//   * Early decided-stores: after bracket pass, T is known to lie in [A,B), so
//     keys < A are definitively zero and keys >= B definitively kept. All such
//     float4 groups (~97%) are stored WHILE wave0 runs the bisection; only
//     groups containing window elements (~460/row) are fixed up after T.
//   * Bisection reads candidates straight from LDS (no creg cache) to stay in
//     the 64-VGPR budget; it is hidden behind the other waves' stores.
// Exact fallback (R2/R4-proven) preserved for arbitrary inputs.
// R6: resubmit unchanged — R5 bench died on container acquisition (infra),
// kernel audit found no hang/OOB path.

constexpr int COLS  = 16384;
constexpr int NT    = 512;             // threads per block (8 waves)
constexpr int PER_T = COLS / NT;       // 32 elements per thread
constexpr int NV4   = PER_T / 4;       // 8 float4 per thread
constexpr int NW    = NT / 64;         // 8 waves
constexpr int CAP   = 2048;            // LDS candidate buffer

typedef float v4f __attribute__((ext_vector_type(4)));

// Monotone float->uint key: order(key) == order(float), all finite values.
__device__ __forceinline__ unsigned int f2key(float f) {
  unsigned int b = __float_as_uint(f);
  return b ^ ((unsigned int)((int)b >> 31) | 0x80000000u);
}
__device__ __forceinline__ float key2f(unsigned int k) {
  unsigned int b = (k & 0x80000000u) ? (k ^ 0x80000000u) : ~k;
  return __uint_as_float(b);
}

__global__ void __launch_bounds__(NT, 8)
topk_scatter_kernel(const float* __restrict__ x, const int* __restrict__ kptr,
                    float* __restrict__ out) {
  const int t    = threadIdx.x;
  const int lane = t & 63;
  const int wid  = t >> 6;
  const long long row = blockIdx.x;
  const int K = *kptr;   // 128

  __shared__ int redA[NW], redB[NW];        // initial bracket counts
  __shared__ int red2[2][NW];               // fallback reduce, parity-buffered
  __shared__ unsigned int cand[CAP];        // compacted candidate keys
  __shared__ int cand_n;
  __shared__ unsigned int sT;               // broadcast: threshold key
  __shared__ int sE, sR;                    // broadcast: eq-count, keep-count
  __shared__ unsigned int flags[COLS / 32]; // rare-path tie bitmask (2 KB)

  const uint4* xrow = reinterpret_cast<const uint4*>(x + row * COLS);
  v4f*         orow = reinterpret_cast<v4f*>(out + row * COLS);

  // ---- load + transform; keys stay in registers (32/thread) -------------
  unsigned int key[PER_T];
  #pragma unroll
  for (int r = 0; r < NV4; ++r) {
    uint4 u = xrow[r * NT + t];
    key[4 * r + 0] = f2key(__uint_as_float(u.x));
    key[4 * r + 1] = f2key(__uint_as_float(u.y));
    key[4 * r + 2] = f2key(__uint_as_float(u.z));
    key[4 * r + 3] = f2key(__uint_as_float(u.w));
  }

  // ---- bracket pass: count >= A and >= B in one register sweep ----------
  const unsigned int A = f2key(1.9f);
  const unsigned int B = f2key(3.2f);
  int cwA = 0, cwB = 0;
  #pragma unroll
  for (int r = 0; r < PER_T; ++r) {
    cwA += __popcll(__ballot(key[r] >= A));
    cwB += __popcll(__ballot(key[r] >= B));
  }
  if (lane == 0) { redA[wid] = cwA; redB[wid] = cwB; }
  if (t == 0) cand_n = 0;
  __syncthreads();                                   // barrier 1
  int cA = 0, cB = 0;
  #pragma unroll
  for (int w = 0; w < NW; ++w) { cA += redA[w]; cB += redB[w]; }

  const bool fast = (cA >= K) && (cB < K) && ((cA - cB) <= CAP);

  if (fast) {
    // ---- compact window candidates to LDS (once) ------------------------
    #pragma unroll
    for (int r = 0; r < PER_T; ++r) {
      const unsigned int kk = key[r];
      if (kk >= A && kk < B) {
        const int p = atomicAdd(&cand_n, 1);
        cand[p] = kk;
      }
    }
    __syncthreads();                                 // barrier 2

    // ---- wave 0: bisection on LDS candidates (no barriers) --------------
    if (wid == 0) {
      const int NC = cA - cB;                        // >=1 guaranteed
      unsigned int lo = A, hi = B - 1u;
      int cnt_lo = cA, cnt_hi1 = cB;
      while (lo < hi) {
        const unsigned int mid = lo + ((hi - lo) >> 1) + 1u;
        int c = cB;
        for (int j0 = 0; j0 < NC; j0 += 64) {
          const unsigned int v = (j0 + lane < NC) ? cand[j0 + lane] : 0u;
          c += __popcll(__ballot(v >= mid));
        }
        if (c >= K) { lo = mid; cnt_lo = c; }
        else        { hi = mid - 1u; cnt_hi1 = c; }
      }
      if (lane == 0) { sT = lo; sE = cnt_lo - cnt_hi1; sR = K - cnt_hi1; }
    }

    // ---- decided stores: overlap with wave0's bisection ------------------
    // T in [A, B-1] guaranteed on the fast path, so kk < A -> zero and
    // kk >= B -> kept, independent of the final T. ~97% of elements.
    unsigned int defer = 0;
    #pragma unroll
    for (int r = 0; r < NV4; ++r) {
      bool anyw = false;
      v4f vals;
      #pragma unroll
      for (int j = 0; j < 4; ++j) {
        const unsigned int kk = key[4 * r + j];
        anyw = anyw || (kk >= A && kk < B);
        vals[j] = (kk >= B) ? key2f(kk) : 0.0f;
      }
      if (anyw) {
        defer |= (1u << r);
      } else {
        __builtin_nontemporal_store(vals, &orow[r * NT + t]);
      }
    }
    __syncthreads();                                 // barrier 3
    const unsigned int T = sT;
    const int E = sE, R = sR;
    const bool need_rank = (E != R);   // duplicates straddling the boundary

    if (need_rank) {
      // rare path: mark all equal elements, keep the R lowest-indexed ones
      for (int w = t; w < COLS / 32; w += NT) flags[w] = 0u;
      __syncthreads();
      #pragma unroll
      for (int r = 0; r < NV4; ++r) {
        #pragma unroll
        for (int j = 0; j < 4; ++j) {
          if (key[4 * r + j] == T) {
            const int col = (r * NT + t) * 4 + j;
            atomicOr(&flags[col >> 5], 1u << (col & 31));
          }
        }
      }
      __syncthreads();
    }

    // ---- fix-up pass: only groups containing window elements -------------
    #pragma unroll
    for (int r = 0; r < NV4; ++r) {
      if (!(defer & (1u << r))) continue;
      v4f vals;
      #pragma unroll
      for (int j = 0; j < 4; ++j) {
        const unsigned int kk = key[4 * r + j];
        bool keep;
        if (kk > T) {
          keep = true;
        } else if (kk == T) {
          if (!need_rank) {
            keep = true;
          } else {
            const int col = (r * NT + t) * 4 + j;
            const int w_hi = col >> 5;
            int rank = 0;
            for (int w = 0; w < w_hi; ++w) rank += __popc(flags[w]);
            rank += __popc(flags[w_hi] & ((1u << (col & 31)) - 1u));
            keep = (rank < R);
          }
        } else {
          keep = false;
        }
        vals[j] = keep ? key2f(kk) : 0.0f;
      }
      __builtin_nontemporal_store(vals, &orow[r * NT + t]);
    }
    return;
  }

  // ---- exact fallback: full bitwise bisection (R2/R4-proven) -------------
  unsigned int T;
  int E, R;
  {
    unsigned int lo = 0u, hi = 0xFFFFFFFFu;
    int cnt_lo = COLS, cnt_hi1 = 0;
    int base = 0, cN = 0;
    bool compacted = false;
    int par = 0;
    while (lo < hi) {
      const unsigned int mid = lo + ((hi - lo) >> 1) + 1u;
      int c;
      if (!compacted) {
        int cw = 0;
        #pragma unroll
        for (int r = 0; r < PER_T; ++r)
          cw += __popcll(__ballot(key[r] >= mid));
        if (lane == 0) red2[par][wid] = cw;
        __syncthreads();
        c = 0;
        #pragma unroll
        for (int w = 0; w < NW; ++w) c += red2[par][w];
        par ^= 1;
      } else {
        int cw = 0;
        for (int j0 = 0; j0 < cN; j0 += 64) {
          const int j = j0 + lane;
          const unsigned int v = (j < cN) ? cand[j] : 0u;
          cw += __popcll(__ballot(v >= mid));
        }
        c = base + cw;
      }
      if (c >= K) { lo = mid; cnt_lo = c; }
      else        { hi = mid - 1u; cnt_hi1 = c; }

      if (!compacted && lo < hi && (cnt_lo - cnt_hi1) <= CAP) {
        if (t == 0) cand_n = 0;
        __syncthreads();
        #pragma unroll
        for (int r = 0; r < PER_T; ++r) {
          const unsigned int kk = key[r];
          if (kk >= lo && kk <= hi) {
            const int p = atomicAdd(&cand_n, 1);
            cand[p] = kk;
          }
        }
        __syncthreads();
        cN = cnt_lo - cnt_hi1;
        base = cnt_hi1;
        compacted = true;
      }
    }
    T = lo; E = cnt_lo - cnt_hi1; R = K - cnt_hi1;
  }

  const bool need_rank = (E != R);

  if (need_rank) {
    for (int w = t; w < COLS / 32; w += NT) flags[w] = 0u;
    __syncthreads();
    #pragma unroll
    for (int r = 0; r < NV4; ++r) {
      #pragma unroll
      for (int j = 0; j < 4; ++j) {
        if (key[4 * r + j] == T) {
          const int col = (r * NT + t) * 4 + j;
          atomicOr(&flags[col >> 5], 1u << (col & 31));
        }
      }
    }
    __syncthreads();
  }

  // ---- full write pass (fallback only) -----------------------------------
  #pragma unroll
  for (int r = 0; r < NV4; ++r) {
    v4f vals;
    #pragma unroll
    for (int j = 0; j < 4; ++j) {
      const unsigned int kk = key[4 * r + j];
      bool keep;
      if (kk > T) {
        keep = true;
      } else if (kk == T) {
        if (!need_rank) {
          keep = true;
        } else {
          const int col = (r * NT + t) * 4 + j;
          const int w_hi = col >> 5;
          int rank = 0;
          for (int w = 0; w < w_hi; ++w) rank += __popc(flags[w]);
          rank += __popc(flags[w_hi] & ((1u << (col & 31)) - 1u));
          keep = (rank < R);
        }
      } else {
        keep = false;
      }
      vals[j] = keep ? key2f(kk) : 0.0f;
    }
    __builtin_nontemporal_store(vals, &orow[r * NT + t]);
  }
}

extern "C" void kernel_launch(void* const* d_in, const int* in_sizes, int n_in,
                              void* d_out, int out_size, void* d_ws, size_t ws_size,
                              hipStream_t stream) {
  const float* x    = (const float*)d_in[0];
  const int*   kptr = (const int*)d_in[1];
  float*       out  = (float*)d_out;
  const int rows = in_sizes[0] / COLS;  // 4096
  topk_scatter_kernel<<<rows, NT, 0, stream>>>(x, kptr, out);
}

// Round 3
// 479.187 us; speedup vs baseline: 1.2014x; 1.2014x over previous
//
#include <hip/hip_runtime.h>

// TopKActivation: per row of [4096, 16384] fp32, keep top-k (k=128), zero rest.
// R6 post-mortem: PER_T=32 register-resident keys SPILLED (VGPR_Count stuck at
// 32; WRITE_SIZE 262->469MB = +207MB scratch writes; dur 164->287us). The
// register-resident-key design is the constraint. R7 = streaming design:
//   * No keys held across phases. One fused pass: load uint4 -> count vs
//     constants A/B -> push window candidates (key+col) to LDS -> store the
//     decided output for EVERY group immediately (window lanes 0 for now).
//   * Wave0 selects T from a 64-bin histogram: suffix-scan -> threshold bin ->
//     <=128 bin-cands compacted to regs -> 17-iteration ballot bisect.
//   * Fix-up = ~(K - cB) scalar stores of kept window values. No re-reads.
//   * NT=256, launch_bounds(256,8): ~48 VGPR, 15KB LDS -> 8 blocks/CU
//     (32 waves = full occupancy), 8 rows streaming per CU.
// Exact fallback (bitwise bisect with global re-reads + compaction) preserves
// correctness for arbitrary inputs; never taken for N(0,1) rows.

constexpr int COLS = 16384;
constexpr int NT   = 256;             // threads per block (4 waves)
constexpr int NG   = COLS / 4;        // 4096 float4-groups per row
constexpr int GPT  = NG / NT;         // 16 groups per thread
constexpr int NW   = NT / 64;         // 4 waves
constexpr int CAP  = 2048;            // LDS candidate buffer
constexpr int NBIN = 64;              // histogram bins over [A, B)

typedef float v4f __attribute__((ext_vector_type(4)));

// Monotone float->uint key: order(key) == order(float), all finite values.
__device__ __forceinline__ unsigned int f2key(float f) {
  unsigned int b = __float_as_uint(f);
  return b ^ ((unsigned int)((int)b >> 31) | 0x80000000u);
}
__device__ __forceinline__ float key2f(unsigned int k) {
  unsigned int b = (k & 0x80000000u) ? (k ^ 0x80000000u) : ~k;
  return __uint_as_float(b);
}

__global__ void __launch_bounds__(NT, 8)
topk_scatter_kernel(const float* __restrict__ x, const int* __restrict__ kptr,
                    float* __restrict__ out) {
  const int t    = threadIdx.x;
  const int lane = t & 63;
  const int wid  = t >> 6;
  const long long row = blockIdx.x;
  const int K = *kptr;   // 128

  __shared__ int redA[NW], redB[NW];        // bracket counts per wave
  __shared__ int red2[2][NW];               // fallback reduce, parity-buffered
  __shared__ unsigned int   cand[CAP];      // window candidate keys
  __shared__ unsigned short candcol[CAP];   // window candidate columns
  __shared__ int hist[NBIN];                // window histogram
  __shared__ int cand_n;
  __shared__ int c2n;                       // wave0 bin-compaction counter
  __shared__ unsigned int sT;               // broadcast: threshold key
  __shared__ int sE, sR;                    // broadcast: eq-count, keep-count
  __shared__ unsigned int flags[COLS / 32]; // fallback tie bitmask (2 KB);
                                            // reused as wave0's cand2[128]

  const uint4* xrow = reinterpret_cast<const uint4*>(x + row * COLS);
  v4f*         orow = reinterpret_cast<v4f*>(out + row * COLS);

  // Window [A, B): key range B-A = 0x59999A < 2^23, so bin = (k-A)>>17 < 64.
  const unsigned int A = f2key(1.9f);
  const unsigned int B = f2key(3.2f);

  if (t < NBIN) hist[t] = 0;
  if (t == 0) cand_n = 0;
  __syncthreads();                                   // barrier 0

  // ---- fused pass: load, count, push window cands, store decided output --
  int cwA = 0, cwB = 0;
  #pragma unroll 4
  for (int r = 0; r < GPT; ++r) {
    const int g = r * NT + t;
    const uint4 u = xrow[g];
    const unsigned int k0 = f2key(__uint_as_float(u.x));
    const unsigned int k1 = f2key(__uint_as_float(u.y));
    const unsigned int k2 = f2key(__uint_as_float(u.z));
    const unsigned int k3 = f2key(__uint_as_float(u.w));
    cwA += (k0 >= A) + (k1 >= A) + (k2 >= A) + (k3 >= A);
    cwB += (k0 >= B) + (k1 >= B) + (k2 >= B) + (k3 >= B);
    const bool w0 = (k0 >= A) & (k0 < B);
    const bool w1 = (k1 >= A) & (k1 < B);
    const bool w2 = (k2 >= A) & (k2 < B);
    const bool w3 = (k3 >= A) & (k3 < B);
    if (w0 | w1 | w2 | w3) {
      if (w0) { const int p = atomicAdd(&cand_n, 1);
                if (p < CAP) { cand[p] = k0; candcol[p] = (unsigned short)(4*g+0); }
                atomicAdd(&hist[(k0 - A) >> 17], 1); }
      if (w1) { const int p = atomicAdd(&cand_n, 1);
                if (p < CAP) { cand[p] = k1; candcol[p] = (unsigned short)(4*g+1); }
                atomicAdd(&hist[(k1 - A) >> 17], 1); }
      if (w2) { const int p = atomicAdd(&cand_n, 1);
                if (p < CAP) { cand[p] = k2; candcol[p] = (unsigned short)(4*g+2); }
                atomicAdd(&hist[(k2 - A) >> 17], 1); }
      if (w3) { const int p = atomicAdd(&cand_n, 1);
                if (p < CAP) { cand[p] = k3; candcol[p] = (unsigned short)(4*g+3); }
                atomicAdd(&hist[(k3 - A) >> 17], 1); }
    }
    v4f vals;
    vals[0] = (k0 >= B) ? __uint_as_float(u.x) : 0.0f;
    vals[1] = (k1 >= B) ? __uint_as_float(u.y) : 0.0f;
    vals[2] = (k2 >= B) ? __uint_as_float(u.z) : 0.0f;
    vals[3] = (k3 >= B) ? __uint_as_float(u.w) : 0.0f;
    __builtin_nontemporal_store(vals, &orow[g]);
  }
  #pragma unroll
  for (int off = 32; off; off >>= 1) {
    cwA += __shfl_down(cwA, off);
    cwB += __shfl_down(cwB, off);
  }
  if (lane == 0) { redA[wid] = cwA; redB[wid] = cwB; }
  __syncthreads();                                   // barrier 1

  int cA = 0, cBv = 0;
  #pragma unroll
  for (int w = 0; w < NW; ++w) { cA += redA[w]; cBv += redB[w]; }

  const bool fast = (cA >= K) && (cBv < K) && ((cA - cBv) <= CAP);

  if (fast) {
    const int NC = cA - cBv;                         // exact window count
    // ---- wave 0: histogram select + tiny bisect (no barriers) -----------
    if (wid == 0) {
      // suffix sums: suf[b] = count of window cands with bin >= b
      int suf = hist[lane];                          // NBIN == 64 lanes
      #pragma unroll
      for (int off = 1; off < 64; off <<= 1) {
        const int v = __shfl_down(suf, off);
        if (lane + off < 64) suf += v;
      }
      const unsigned long long m = __ballot(cBv + suf >= K);
      const int bstar = 63 - __clzll((long long)m);  // threshold bin
      const int s_b  = __shfl(suf, bstar);
      const int s_b1 = (bstar < 63) ? __shfl(suf, bstar + 1) : 0;
      const int nb = s_b - s_b1;                     // cands in bin (>=1)
      const unsigned int binlo = A + ((unsigned int)bstar << 17);
      const unsigned int binhi = binlo + (1u << 17) - 1u;
      unsigned int lo, hi;
      int cnt_lo, cnt_hi1;
      if (nb <= 128) {
        // compact bin-b* cands into cand2 (reuse flags); intra-wave ordered
        unsigned int* cand2 = (unsigned int*)flags;
        cand2[lane] = 0u; cand2[64 + lane] = 0u;     // 0 < binlo: never counts
        if (lane == 0) c2n = 0;
        for (int j0 = 0; j0 < NC; j0 += 64) {
          const int j = j0 + lane;
          const unsigned int v = (j < NC) ? cand[j] : 0u;
          if (v >= binlo && v <= binhi) {
            const int p = atomicAdd(&c2n, 1);
            cand2[p] = v;
          }
        }
        const unsigned int r0 = cand2[lane];
        const unsigned int r1 = cand2[64 + lane];
        lo = binlo; hi = binhi;
        cnt_lo = cBv + s_b; cnt_hi1 = cBv + s_b1;
        const int base2 = cBv + s_b1;
        while (lo < hi) {                            // exactly 17 iterations
          const unsigned int mid = lo + ((hi - lo) >> 1) + 1u;
          const int c = base2 + __popcll(__ballot(r0 >= mid))
                              + __popcll(__ballot(r1 >= mid));
          if (c >= K) { lo = mid; cnt_lo = c; }
          else        { hi = mid - 1u; cnt_hi1 = c; }
        }
      } else {
        // adversarial bin (>128 cands): scan full cand list per iteration
        lo = A; hi = B - 1u; cnt_lo = cA; cnt_hi1 = cBv;
        while (lo < hi) {
          const unsigned int mid = lo + ((hi - lo) >> 1) + 1u;
          int c = cBv;
          for (int j0 = 0; j0 < NC; j0 += 64) {
            const unsigned int v = (j0 + lane < NC) ? cand[j0 + lane] : 0u;
            c += __popcll(__ballot(v >= mid));
          }
          if (c >= K) { lo = mid; cnt_lo = c; }
          else        { hi = mid - 1u; cnt_hi1 = c; }
        }
      }
      if (lane == 0) { sT = lo; sE = cnt_lo - cnt_hi1; sR = K - cnt_hi1; }
    }
    __syncthreads();                                 // barrier 2

    // ---- fix-up: scatter kept window values (~K - cB scalar stores) ------
    const unsigned int T = sT;
    const int Ev = sE, Rv = sR;
    const bool needR = (Ev != Rv);     // duplicates straddling the boundary
    float* orow_s = out + row * COLS;
    for (int i = t; i < NC; i += NT) {
      const unsigned int k = cand[i];
      if (k < T) continue;
      const int col = candcol[i];
      if (needR && k == T) {
        int rk = 0;
        for (int j = 0; j < NC; ++j)
          rk += (cand[j] == T && candcol[j] < col) ? 1 : 0;
        if (rk >= Rv) continue;        // keep only R lowest-indexed ties
      }
      orow_s[col] = key2f(k);
    }
    return;
  }

  // ---- exact fallback: bitwise bisection with global re-reads ------------
  unsigned int T;
  int Ev, Rv;
  {
    unsigned int lo = 0u, hi = 0xFFFFFFFFu;
    int cnt_lo = COLS, cnt_hi1 = 0;
    int base = 0, cN = 0;
    bool compacted = false;
    int par = 0;
    while (lo < hi) {
      const unsigned int mid = lo + ((hi - lo) >> 1) + 1u;
      int c;
      if (!compacted) {
        int cw = 0;
        for (int r = 0; r < GPT; ++r) {
          const uint4 u = xrow[r * NT + t];
          cw += (f2key(__uint_as_float(u.x)) >= mid);
          cw += (f2key(__uint_as_float(u.y)) >= mid);
          cw += (f2key(__uint_as_float(u.z)) >= mid);
          cw += (f2key(__uint_as_float(u.w)) >= mid);
        }
        #pragma unroll
        for (int off = 32; off; off >>= 1) cw += __shfl_down(cw, off);
        if (lane == 0) red2[par][wid] = cw;
        __syncthreads();
        c = 0;
        #pragma unroll
        for (int w = 0; w < NW; ++w) c += red2[par][w];
        par ^= 1;
      } else {
        int cw = 0;
        for (int j0 = 0; j0 < cN; j0 += 64) {
          const int j = j0 + lane;
          const unsigned int v = (j < cN) ? cand[j] : 0u;
          cw += __popcll(__ballot(v >= mid));
        }
        c = base + cw;
      }
      if (c >= K) { lo = mid; cnt_lo = c; }
      else        { hi = mid - 1u; cnt_hi1 = c; }

      if (!compacted && lo < hi && (cnt_lo - cnt_hi1) <= CAP) {
        if (t == 0) cand_n = 0;
        __syncthreads();
        for (int r = 0; r < GPT; ++r) {
          const uint4 u = xrow[r * NT + t];
          const unsigned int kk[4] = {
            f2key(__uint_as_float(u.x)), f2key(__uint_as_float(u.y)),
            f2key(__uint_as_float(u.z)), f2key(__uint_as_float(u.w)) };
          #pragma unroll
          for (int j = 0; j < 4; ++j) {
            if (kk[j] >= lo && kk[j] <= hi) {
              const int p = atomicAdd(&cand_n, 1);
              if (p < CAP) cand[p] = kk[j];
            }
          }
        }
        __syncthreads();
        cN = cnt_lo - cnt_hi1;
        base = cnt_hi1;
        compacted = true;
      }
    }
    T = lo; Ev = cnt_lo - cnt_hi1; Rv = K - cnt_hi1;
  }

  const bool needR = (Ev != Rv);
  if (needR) {
    for (int w = t; w < COLS / 32; w += NT) flags[w] = 0u;
    __syncthreads();
    for (int r = 0; r < GPT; ++r) {
      const int g = r * NT + t;
      const uint4 u = xrow[g];
      const unsigned int kk[4] = {
        f2key(__uint_as_float(u.x)), f2key(__uint_as_float(u.y)),
        f2key(__uint_as_float(u.z)), f2key(__uint_as_float(u.w)) };
      #pragma unroll
      for (int j = 0; j < 4; ++j) {
        if (kk[j] == T) {
          const int col = 4 * g + j;
          atomicOr(&flags[col >> 5], 1u << (col & 31));
        }
      }
    }
    __syncthreads();
  }

  // full write pass (fallback only; overwrites phase-1 stores)
  for (int r = 0; r < GPT; ++r) {
    const int g = r * NT + t;
    const uint4 u = xrow[g];
    const unsigned int kk[4] = {
      f2key(__uint_as_float(u.x)), f2key(__uint_as_float(u.y)),
      f2key(__uint_as_float(u.z)), f2key(__uint_as_float(u.w)) };
    v4f vals;
    #pragma unroll
    for (int j = 0; j < 4; ++j) {
      bool keep;
      if (kk[j] > T) {
        keep = true;
      } else if (kk[j] == T) {
        if (!needR) {
          keep = true;
        } else {
          const int col = 4 * g + j;
          const int w_hi = col >> 5;
          int rank = 0;
          for (int w = 0; w < w_hi; ++w) rank += __popc(flags[w]);
          rank += __popc(flags[w_hi] & ((1u << (col & 31)) - 1u));
          keep = (rank < Rv);
        }
      } else {
        keep = false;
      }
      vals[j] = keep ? key2f(kk[j]) : 0.0f;
    }
    __builtin_nontemporal_store(vals, &orow[g]);
  }
}

extern "C" void kernel_launch(void* const* d_in, const int* in_sizes, int n_in,
                              void* d_out, int out_size, void* d_ws, size_t ws_size,
                              hipStream_t stream) {
  const float* x    = (const float*)d_in[0];
  const int*   kptr = (const int*)d_in[1];
  float*       out  = (float*)d_out;
  const int rows = in_sizes[0] / COLS;  // 4096
  topk_scatter_kernel<<<rows, NT, 0, stream>>>(x, kptr, out);
}